// Round 4
// baseline (545.896 us; speedup 1.0000x reference)
//
#include <hip/hip_runtime.h>

// SpikingNetwork: B=128 T=128 I=1024 H1=2048 H2=2048 O=512
// R4: fused GEMM+LIF ported to counted-vmcnt pipelined schedule:
//   BM=256 BN=128 BK=64, 8 waves (4Mx2N), 3 LDS slots (144KB), stage t+2
//   during t, vmcnt(6) per K-tile boundary, 2 phases/K-tile, T2 XOR-swizzle
//   (slot ^= row&7) via pre-swizzled global source + swizzled ds_read,
//   setprio around MFMA. Numerics: GEMM1 3-term split-bf16 (K'=3072),
//   GEMM2 2-term (A=binary s1 exact, K'=4096), GEMM3 split-K atomic.

typedef unsigned long long u64;
typedef __attribute__((ext_vector_type(4))) float f32x4;
typedef __attribute__((ext_vector_type(8))) short bf16x8;

__device__ __forceinline__ unsigned short f2bf(float f) {
  unsigned u = __float_as_uint(f);
  u += 0x7fff + ((u >> 16) & 1);   // RNE
  return (unsigned short)(u >> 16);
}
__device__ __forceinline__ float bf2f(unsigned short h) {
  return __uint_as_float(((unsigned)h) << 16);
}
__device__ __forceinline__ void gld_lds16(const unsigned short* g, unsigned short* l) {
  __builtin_amdgcn_global_load_lds((const __attribute__((address_space(1))) void*)g,
                                   (__attribute__((address_space(3))) void*)l, 16, 0, 0);
}

// src: R x K f32 (K = 1<<lgK) -> dst: R x 2K bf16 rows [hi | lo]
__global__ void k_split(const float* __restrict__ src, unsigned short* __restrict__ dst,
                        int lgK, size_t total) {
  size_t i = (size_t)blockIdx.x * 256 + threadIdx.x;
  if (i >= total) return;
  const int K = 1 << lgK;
  size_t r = i >> lgK;
  int k = (int)(i & (size_t)(K - 1));
  float f = src[i];
  unsigned short hi = f2bf(f);
  unsigned short lo = f2bf(f - bf2f(hi));
  size_t o = (r << (lgK + 1)) + (size_t)k;
  dst[o] = hi;
  dst[o + K] = lo;
}

// Fused pipelined GEMM + LIF. Tile 256x128; rows = 2 batch elements' full
// time series (t fastest). LAYER 1: NKT=48 (3-term); LAYER 2: NKT=64 (2-term).
template <int LAYER>
__global__ __launch_bounds__(512, 2)
void k_gemm_lif(const unsigned short* __restrict__ A,
                const unsigned short* __restrict__ Bw,
                const float* __restrict__ bias,
                unsigned short* __restrict__ out, int b0) {
  __shared__ __align__(128) char lds[147456];   // 3 slots x (A 32KB + B 16KB)
  const int NKT = (LAYER == 1) ? 48 : 64;
  const int ldB = (LAYER == 1) ? 2048 : 4096;
  const int tid  = threadIdx.x;
  const int lane = tid & 63;
  const int w    = tid >> 6;                 // 0..7
  const int wr   = (w >> 1) * 64;            // 0,64,128,192
  const int wc   = (w & 1) * 64;             // 0,64
  const int lrow = lane & 15;
  const int t4   = lane >> 4;                // 0..3
  const int brow = blockIdx.x * 256;
  const int bcol = blockIdx.y * 128;

  f32x4 acc[4][4];
#pragma unroll
  for (int m = 0; m < 4; ++m)
#pragma unroll
    for (int n = 0; n < 4; ++n) acc[m][n] = (f32x4){0.f, 0.f, 0.f, 0.f};

  // Stage half (3 of 6 chunks) of K-tile tt into slot tt%3.
  // LDS dest linear (gld_lds constraint); source col pre-swizzled by
  // slot^(row&7) so swizzled ds_read recovers linear K (rule #21).
  auto stage3 = [&](int tt, int half) {
    if (tt >= NKT) return;
    const int kb = tt * 64;
    int aoff, boff;
    if (LAYER == 1) {
      aoff = (kb < 1024) ? kb : kb - 1024;    // [Xhi,Xhi,Xlo]
      boff = (kb < 2048) ? kb : kb - 2048;    // [W1hi,W1lo,W1hi]
    } else {
      aoff = kb & 2047;                        // binary S1 twice
      boff = kb;                               // [W2hi|W2lo]
    }
    char* lb = lds + (tt % 3) * 49152;
#pragma unroll
    for (int ii = 0; ii < 3; ++ii) {
      const int c = tid + (half * 3 + ii) * 512;
      if (c < 2048) {                          // A: 256 rows x 8 slots
        const int row  = c >> 3;
        const int scol = ((c & 7) ^ (row & 7)) * 8;
        gld_lds16(A + (size_t)(brow + row) * 2048 + (aoff + scol),
                  (unsigned short*)(lb + c * 16));
      } else {                                 // B: 128 rows x 8 slots
        const int cb   = c - 2048;
        const int row  = cb >> 3;
        const int scol = ((cb & 7) ^ (row & 7)) * 8;
        gld_lds16(Bw + (size_t)(bcol + row) * ldB + (boff + scol),
                  (unsigned short*)(lb + 32768 + cb * 16));
      }
    }
  };

  // prologue: stage tiles 0,1 (12 loads); wait until tile 0 landed (6 left)
  stage3(0, 0); stage3(0, 1);
  stage3(1, 0); stage3(1, 1);
  asm volatile("s_waitcnt vmcnt(6)" ::: "memory");
  __builtin_amdgcn_s_barrier();

#pragma unroll 1
  for (int t = 0; t < NKT; ++t) {
    const char* sb = lds + (t % 3) * 49152;
#pragma unroll
    for (int ks = 0; ks < 2; ++ks) {
      bf16x8 af[4], bg[4];
#pragma unroll
      for (int m = 0; m < 4; ++m) {
        const int row = wr + m * 16 + lrow;
        const int sl  = (ks * 4 + t4) ^ (row & 7);
        af[m] = *(const bf16x8*)(sb + row * 128 + sl * 16);
      }
#pragma unroll
      for (int n = 0; n < 4; ++n) {
        const int row = wc + n * 16 + lrow;
        const int sl  = (ks * 4 + t4) ^ (row & 7);
        bg[n] = *(const bf16x8*)(sb + 32768 + row * 128 + sl * 16);
      }
      stage3(t + 2, ks);                        // prefetch 2 K-tiles ahead
      __builtin_amdgcn_s_barrier();
      asm volatile("s_waitcnt lgkmcnt(0)" ::: "memory");
      __builtin_amdgcn_sched_barrier(0);
      __builtin_amdgcn_s_setprio(1);
#pragma unroll
      for (int m = 0; m < 4; ++m)
#pragma unroll
        for (int n = 0; n < 4; ++n)
          acc[m][n] = __builtin_amdgcn_mfma_f32_16x16x32_bf16(af[m], bg[n], acc[m][n], 0, 0, 0);
      __builtin_amdgcn_s_setprio(0);
      if (ks == 0) {
        __builtin_amdgcn_s_barrier();
      } else {
        // K-tile boundary: tile t+1 must be fully landed for ALL waves.
        // If we staged t+2 this tile, leave its 6 loads in flight.
        if (t + 2 < NKT) asm volatile("s_waitcnt vmcnt(6)" ::: "memory");
        else             asm volatile("s_waitcnt vmcnt(0)" ::: "memory");
        __builtin_amdgcn_s_barrier();
      }
    }
  }

  // ---- fused LIF epilogue (LDS reused as 128x132 f32 C-half) ----
  float* Ct = (float*)lds;
  const int colT = tid & 127;
  const int bb   = (tid >> 7) & 1;           // batch-within-tile for scanners
  const float bs = (tid < 256) ? bias[bcol + colT] : 0.f;
  float v = 0.f;
  int cnt = 0;
  unsigned short* sp = nullptr;
  if (LAYER == 1) sp = out + (size_t)(brow + bb * 128) * 2048 + bcol + colT;
#pragma unroll
  for (int h = 0; h < 2; ++h) {
    __syncthreads();
    if (((w >> 1) & 1) == h) {               // waves owning t-rows [64h,64h+64)
      const int lrb = (wr >= 128) ? 64 : 0;  // batch1 -> local rows 64..127
#pragma unroll
      for (int m = 0; m < 4; ++m)
#pragma unroll
        for (int n = 0; n < 4; ++n) {
          const int lr  = lrb + m * 16 + t4 * 4;
          const int col = wc + n * 16 + lrow;
#pragma unroll
          for (int r = 0; r < 4; ++r) Ct[(lr + r) * 132 + col] = acc[m][n][r];
        }
    }
    __syncthreads();
    if (tid < 256) {
      if (LAYER == 1) {
#pragma unroll 4
        for (int tl = 0; tl < 64; ++tl) {
          const float xx = Ct[(bb * 64 + tl) * 132 + colT] + bs;
          v = 0.9f * xx + v - ((xx > 1.0f) ? 1.0f : 0.0f);
          sp[(size_t)(h * 64 + tl) * 2048] =
              (v > 1.0f) ? (unsigned short)0x3F80 : (unsigned short)0;
        }
      } else {
#pragma unroll 4
        for (int tl = 0; tl < 64; ++tl) {
          const float xx = Ct[(bb * 64 + tl) * 132 + colT] + bs;
          v = 0.9f * xx + v - ((xx > 1.0f) ? 1.0f : 0.0f);
          cnt += (v > 1.0f);
        }
      }
    }
  }
  if (LAYER == 2 && tid < 256)
    out[(size_t)(b0 + 2 * blockIdx.x + bb) * 2048 + bcol + colT] =
        f2bf((float)cnt * 0.0078125f);
}

// out(128x512) += ACC(128x2048 bf16) @ Wocat^T over K-slice z*256..+256, atomic
__global__ void k_gemm3(const unsigned short* __restrict__ A,
                        const unsigned short* __restrict__ B,
                        float* __restrict__ C) {
  __shared__ __align__(16) unsigned short Asm[128 * 64];
  __shared__ __align__(16) unsigned short Bsm[128 * 64];
  const int tid  = threadIdx.x;
  const int bcol = blockIdx.y * 128;
  const int k0   = blockIdx.z * 256;
  const int lane = tid & 63;
  const int w    = tid >> 6;
  const int wr = (w >> 1) * 64, wc = (w & 1) * 64;
  const int lrow = lane & 15, lk = (lane >> 4) * 8;

  f32x4 acc[4][4];
#pragma unroll
  for (int m = 0; m < 4; ++m)
#pragma unroll
    for (int n = 0; n < 4; ++n) acc[m][n] = (f32x4){0.f, 0.f, 0.f, 0.f};

  for (int kt = 0; kt < 4; ++kt) {
    const int kb = k0 + kt * 64;
#pragma unroll
    for (int i = 0; i < 4; ++i) {
      int c = tid + i * 256;
      int row = c >> 3, kc = (c & 7) * 8;
      gld_lds16(A + (size_t)row * 2048 + (kb & 2047) + kc, &Asm[c * 8]);
      gld_lds16(B + (size_t)(bcol + row) * 4096 + kb + kc, &Bsm[c * 8]);
    }
    __syncthreads();
#pragma unroll
    for (int ks = 0; ks < 2; ++ks) {
      bf16x8 af[4], bg[4];
#pragma unroll
      for (int m = 0; m < 4; ++m)
        af[m] = *(const bf16x8*)&Asm[(wr + m * 16 + lrow) * 64 + ks * 32 + lk];
#pragma unroll
      for (int n = 0; n < 4; ++n)
        bg[n] = *(const bf16x8*)&Bsm[(wc + n * 16 + lrow) * 64 + ks * 32 + lk];
#pragma unroll
      for (int m = 0; m < 4; ++m)
#pragma unroll
        for (int n = 0; n < 4; ++n)
          acc[m][n] = __builtin_amdgcn_mfma_f32_16x16x32_bf16(af[m], bg[n], acc[m][n], 0, 0, 0);
    }
    __syncthreads();
  }
#pragma unroll
  for (int m = 0; m < 4; ++m)
#pragma unroll
    for (int n = 0; n < 4; ++n) {
      int r0 = wr + m * 16 + (lane >> 4) * 4;
      int c0 = bcol + wc + n * 16 + (lane & 15);
#pragma unroll
      for (int r = 0; r < 4; ++r)
        atomicAdd(&C[(size_t)(r0 + r) * 512 + c0], acc[m][n][r]);
    }
}

__global__ void k_init_out(float* __restrict__ out, const float* __restrict__ bout) {
  int i = blockIdx.x * 256 + threadIdx.x;   // 128*512
  out[i] = bout[i & 511];
}

extern "C" void kernel_launch(void* const* d_in, const int* in_sizes, int n_in,
                              void* d_out, int out_size, void* d_ws, size_t ws_size,
                              hipStream_t stream) {
  const float* x    = (const float*)d_in[0];
  const float* W1   = (const float*)d_in[1];
  const float* b1   = (const float*)d_in[2];
  const float* W2   = (const float*)d_in[3];
  const float* b2   = (const float*)d_in[4];
  const float* Wout = (const float*)d_in[5];
  const float* bout = (const float*)d_in[6];
  float* out = (float*)d_out;
  (void)in_sizes; (void)n_in; (void)out_size;

  char* ws = (char*)d_ws;
  size_t off = 0;
  auto alloc = [&](size_t bytes) -> void* {
    void* p = ws + off;
    off += (bytes + 255) & ~(size_t)255;
    return p;
  };
  unsigned short* W1cat = (unsigned short*)alloc((size_t)2048 * 2048 * 2);  // 8 MiB
  unsigned short* W2cat = (unsigned short*)alloc((size_t)2048 * 4096 * 2);  // 16 MiB
  unsigned short* Wocat = (unsigned short*)alloc((size_t)512 * 4096 * 2);   // 4 MiB
  unsigned short* ACC   = (unsigned short*)alloc((size_t)128 * 2048 * 2);   // 0.5 MiB
  const size_t fixed = off;

  // largest row-chunk (multiple of 1024 >= 1024) whose Xcat+S1 fit in ws
  int rows_c = 16384;
  while (rows_c > 1024) {
    size_t per = 2 * (((size_t)rows_c * 2048 * 2 + 255) & ~(size_t)255);
    if (fixed + per <= ws_size) break;
    rows_c >>= 1;
  }
  unsigned short* Xcat = (unsigned short*)alloc((size_t)rows_c * 2048 * 2);
  unsigned short* S1c  = (unsigned short*)alloc((size_t)rows_c * 2048 * 2);

  // weight splits (once per call)
  k_split<<<(2048 * 1024 + 255) / 256, 256, 0, stream>>>(W1, W1cat, 10, (size_t)2048 * 1024);
  k_split<<<(2048 * 2048 + 255) / 256, 256, 0, stream>>>(W2, W2cat, 11, (size_t)2048 * 2048);
  k_split<<<(512 * 2048 + 255) / 256, 256, 0, stream>>>(Wout, Wocat, 11, (size_t)512 * 2048);

  const int nch = 16384 / rows_c;
  for (int c = 0; c < nch; ++c) {
    k_split<<<rows_c * 4, 256, 0, stream>>>(x + (size_t)c * rows_c * 1024, Xcat, 10,
                                            (size_t)rows_c * 1024);
    k_gemm_lif<1><<<dim3(rows_c / 256, 16), 512, 0, stream>>>(Xcat, W1cat, b1, S1c, 0);
    k_gemm_lif<2><<<dim3(rows_c / 256, 16), 512, 0, stream>>>(S1c, W2cat, b2, ACC,
                                                              c * (rows_c / 128));
  }
  k_init_out<<<256, 256, 0, stream>>>(out, bout);
  k_gemm3<<<dim3(1, 4, 16), 256, 0, stream>>>(ACC, Wocat, out);
}

// Round 6
// 455.074 us; speedup vs baseline: 1.1996x; 1.1996x over previous
//
#include <hip/hip_runtime.h>

// SpikingNetwork: B=128 T=128 I=1024 H1=2048 H2=2048 O=512
// R6: R5 geometry (256x256 block tile, 8 waves of 128x64, BK=64, 2x64KB
//   dbuf, row-XOR swizzle, 4-phase interleave, fused LIF epilogue) with the
//   vmcnt race FIXED: all 8 prefetch loads of tile t+1 issue at phase 0 of
//   tile t (slot WAR-safe), single vmcnt(0) at end of phase 3 — waits on
//   loads issued ~4 phases (~1400 cyc) earlier, i.e. effectively free.
// Numerics: GEMM1 3-term split-bf16 (K'=3072), GEMM2 2-term (A=binary s1
//   exact in bf16, K'=4096), GEMM3 split-K atomic. All f32 accumulate.

typedef unsigned long long u64;
typedef __attribute__((ext_vector_type(4))) float f32x4;
typedef __attribute__((ext_vector_type(8))) short bf16x8;

__device__ __forceinline__ unsigned short f2bf(float f) {
  unsigned u = __float_as_uint(f);
  u += 0x7fff + ((u >> 16) & 1);   // RNE
  return (unsigned short)(u >> 16);
}
__device__ __forceinline__ float bf2f(unsigned short h) {
  return __uint_as_float(((unsigned)h) << 16);
}
__device__ __forceinline__ void gld_lds16(const unsigned short* g, unsigned short* l) {
  __builtin_amdgcn_global_load_lds((const __attribute__((address_space(1))) void*)g,
                                   (__attribute__((address_space(3))) void*)l, 16, 0, 0);
}

// src: R x K f32 (K = 1<<lgK) -> dst: R x 2K bf16 rows [hi | lo]
__global__ void k_split(const float* __restrict__ src, unsigned short* __restrict__ dst,
                        int lgK, size_t total) {
  size_t i = (size_t)blockIdx.x * 256 + threadIdx.x;
  if (i >= total) return;
  const int K = 1 << lgK;
  size_t r = i >> lgK;
  int k = (int)(i & (size_t)(K - 1));
  float f = src[i];
  unsigned short hi = f2bf(f);
  unsigned short lo = f2bf(f - bf2f(hi));
  size_t o = (r << (lgK + 1)) + (size_t)k;
  dst[o] = hi;
  dst[o + K] = lo;
}

#define RD_A(AF, MH, KS)                                                      \
  _Pragma("unroll")                                                           \
  for (int m = 0; m < 4; ++m) {                                               \
    const int row = wr + (MH)*64 + m * 16 + lrow;                             \
    const int ch  = ((KS)*4 + t4) ^ (row & 7);                                \
    AF[m] = *(const bf16x8*)(As + row * 128 + ch * 16);                       \
  }
#define RD_B(BG, KS)                                                          \
  _Pragma("unroll")                                                           \
  for (int n = 0; n < 4; ++n) {                                               \
    const int row = wc + n * 16 + lrow;                                       \
    const int ch  = ((KS)*4 + t4) ^ (row & 7);                                \
    BG[n] = *(const bf16x8*)(Bs + row * 128 + ch * 16);                       \
  }
#define MFMA16(MH, AF, BG)                                                    \
  _Pragma("unroll")                                                           \
  for (int m = 0; m < 4; ++m)                                                 \
    _Pragma("unroll")                                                         \
    for (int n = 0; n < 4; ++n)                                               \
      acc[(MH)*4 + m][n] = __builtin_amdgcn_mfma_f32_16x16x32_bf16(           \
          AF[m], BG[n], acc[(MH)*4 + m][n], 0, 0, 0);
#define BAR() __builtin_amdgcn_s_barrier()
#define LGKM0()                                                               \
  do {                                                                        \
    asm volatile("s_waitcnt lgkmcnt(0)" ::: "memory");                        \
    __builtin_amdgcn_sched_barrier(0);                                        \
  } while (0)

// Fused pipelined GEMM + LIF. Block tile 256x256 (2 batches' full time
// series x 256 cols). LAYER 1: NKT=48 (3-term); LAYER 2: NKT=64 (2-term).
template <int LAYER>
__global__ __launch_bounds__(512, 1)
void k_gemm_lif(const unsigned short* __restrict__ A,
                const unsigned short* __restrict__ Bw,
                const float* __restrict__ bias,
                unsigned short* __restrict__ out, int b0) {
  __shared__ __align__(128) char lds[132096];  // 2x64KB slots; epi 128x258 f32
  const int NKT = (LAYER == 1) ? 48 : 64;
  const int ldB = (LAYER == 1) ? 2048 : 4096;
  const int tid  = threadIdx.x;
  const int lane = tid & 63;
  const int w    = tid >> 6;                 // 0..7
  const int wm = w >> 2, wn = w & 3;         // 2M x 4N waves
  const int wr = wm * 128, wc = wn * 64;     // wave tile 128x64
  const int lrow = lane & 15, t4 = lane >> 4;
  const int brow = blockIdx.x * 256, bcol = blockIdx.y * 256;

  f32x4 acc[8][4];
#pragma unroll
  for (int m = 0; m < 8; ++m)
#pragma unroll
    for (int n = 0; n < 4; ++n) acc[m][n] = (f32x4){0.f, 0.f, 0.f, 0.f};

  // Stage ALL of K-tile tt (A 256x64 + B 256x64 = 4096 chunks, 8/thread)
  // into slot tt&1. LDS dest linear (gld_lds constraint); global source col
  // pre-swizzled (chunk ^ row&7) so the swizzled ds_read recovers linear K.
  auto stage_tile = [&](int tt) {
    if (tt >= NKT) return;
    const int kb = tt * 64;
    int aoff, boff;
    if (LAYER == 1) {
      aoff = (kb < 1024) ? kb : kb - 1024;    // [Xhi,Xhi,Xlo]
      boff = (kb < 2048) ? kb : kb - 2048;    // [W1hi,W1lo,W1hi]
    } else {
      aoff = kb & 2047;                        // binary S1 twice
      boff = kb;                               // [W2hi|W2lo]
    }
    char* slot = lds + (tt & 1) * 65536;
#pragma unroll
    for (int j = 0; j < 4; ++j) {              // A: 2048 chunks
      const int c = tid + j * 512;
      const int r = c >> 3;
      const int scol = ((c & 7) ^ (r & 7)) * 8;
      gld_lds16(A + (size_t)(brow + r) * 2048 + aoff + scol,
                (unsigned short*)(slot + c * 16));
    }
#pragma unroll
    for (int j = 0; j < 4; ++j) {              // B: 2048 chunks
      const int c = tid + j * 512;
      const int r = c >> 3;
      const int scol = ((c & 7) ^ (r & 7)) * 8;
      gld_lds16(Bw + (size_t)(bcol + r) * ldB + boff + scol,
                (unsigned short*)(slot + 32768 + c * 16));
    }
  };

  // prologue: tile 0 staged and fully landed
  stage_tile(0);
  asm volatile("s_waitcnt vmcnt(0)" ::: "memory");
  BAR();

#pragma unroll 1
  for (int t = 0; t < NKT; ++t) {
    const char* As = lds + (t & 1) * 65536;
    const char* Bs = As + 32768;
    bf16x8 af[4], bg[4];
    // ---- phase 0: ks0, rows 0-63 of wave tile; prefetch ALL of t+1 ----
    RD_A(af, 0, 0); RD_B(bg, 0);
    stage_tile(t + 1);
    BAR(); LGKM0();
    __builtin_amdgcn_s_setprio(1); MFMA16(0, af, bg); __builtin_amdgcn_s_setprio(0);
    BAR();
    // ---- phase 1: ks0, rows 64-127 ----
    RD_A(af, 1, 0);
    BAR(); LGKM0();
    __builtin_amdgcn_s_setprio(1); MFMA16(1, af, bg); __builtin_amdgcn_s_setprio(0);
    BAR();
    // ---- phase 2: ks1, rows 0-63 ----
    RD_A(af, 0, 1); RD_B(bg, 1);
    BAR(); LGKM0();
    __builtin_amdgcn_s_setprio(1); MFMA16(0, af, bg); __builtin_amdgcn_s_setprio(0);
    BAR();
    // ---- phase 3: ks1, rows 64-127; then wait for t+1 (issued 4 phases
    // ago -> effectively free) so next phase 0 may read any half-tile ----
    RD_A(af, 1, 1);
    BAR(); LGKM0();
    __builtin_amdgcn_s_setprio(1); MFMA16(1, af, bg); __builtin_amdgcn_s_setprio(0);
    asm volatile("s_waitcnt vmcnt(0)" ::: "memory");
    BAR();
  }

  // ---- fused LIF epilogue: two 64-t halves, 128x258 f32 LDS tile ----
  float* Ct = (float*)lds;
  const int colT  = tid & 255;
  const int batch = tid >> 8;                // 2 batches x 256 cols = 512 scanners
  const float bs = bias[bcol + colT];
  float v = 0.f;
  int cnt = 0;
  unsigned short* sp = nullptr;
  if (LAYER == 1) sp = out + (size_t)(brow + batch * 128) * 2048 + bcol + colT;
#pragma unroll
  for (int h = 0; h < 2; ++h) {
    __syncthreads();
#pragma unroll
    for (int mm = 0; mm < 4; ++mm) {
      const int m = h * 4 + mm;              // frag m covers t = m*16..m*16+15
#pragma unroll
      for (int n = 0; n < 4; ++n) {
        const int lr  = wm * 64 + mm * 16 + t4 * 4;   // batch*64 + t-within-half
        const int col = wc + n * 16 + lrow;
#pragma unroll
        for (int r = 0; r < 4; ++r) Ct[(lr + r) * 258 + col] = acc[m][n][r];
      }
    }
    __syncthreads();
    if (LAYER == 1) {
#pragma unroll 4
      for (int tl = 0; tl < 64; ++tl) {
        const float xx = Ct[(batch * 64 + tl) * 258 + colT] + bs;
        v = 0.9f * xx + v - ((xx > 1.0f) ? 1.0f : 0.0f);
        sp[(size_t)(h * 64 + tl) * 2048] =
            (v > 1.0f) ? (unsigned short)0x3F80 : (unsigned short)0;
      }
    } else {
#pragma unroll 4
      for (int tl = 0; tl < 64; ++tl) {
        const float xx = Ct[(batch * 64 + tl) * 258 + colT] + bs;
        v = 0.9f * xx + v - ((xx > 1.0f) ? 1.0f : 0.0f);
        cnt += (v > 1.0f);
      }
    }
  }
  if (LAYER == 2)
    out[(size_t)(b0 + 2 * blockIdx.x + batch) * 2048 + bcol + colT] =
        f2bf((float)cnt * 0.0078125f);
}

// out(128x512) += ACC(128x2048 bf16) @ Wocat^T over K-slice z*256..+256, atomic
__global__ void k_gemm3(const unsigned short* __restrict__ A,
                        const unsigned short* __restrict__ B,
                        float* __restrict__ C) {
  __shared__ __align__(16) unsigned short Asm[128 * 64];
  __shared__ __align__(16) unsigned short Bsm[128 * 64];
  const int tid  = threadIdx.x;
  const int bcol = blockIdx.y * 128;
  const int k0   = blockIdx.z * 256;
  const int lane = tid & 63;
  const int w    = tid >> 6;
  const int wr = (w >> 1) * 64, wc = (w & 1) * 64;
  const int lrow = lane & 15, lk = (lane >> 4) * 8;

  f32x4 acc[4][4];
#pragma unroll
  for (int m = 0; m < 4; ++m)
#pragma unroll
    for (int n = 0; n < 4; ++n) acc[m][n] = (f32x4){0.f, 0.f, 0.f, 0.f};

  for (int kt = 0; kt < 4; ++kt) {
    const int kb = k0 + kt * 64;
#pragma unroll
    for (int i = 0; i < 4; ++i) {
      int c = tid + i * 256;
      int row = c >> 3, kc = (c & 7) * 8;
      gld_lds16(A + (size_t)row * 2048 + (kb & 2047) + kc, &Asm[c * 8]);
      gld_lds16(B + (size_t)(bcol + row) * 4096 + kb + kc, &Bsm[c * 8]);
    }
    __syncthreads();
#pragma unroll
    for (int ks = 0; ks < 2; ++ks) {
      bf16x8 af[4], bg[4];
#pragma unroll
      for (int m = 0; m < 4; ++m)
        af[m] = *(const bf16x8*)&Asm[(wr + m * 16 + lrow) * 64 + ks * 32 + lk];
#pragma unroll
      for (int n = 0; n < 4; ++n)
        bg[n] = *(const bf16x8*)&Bsm[(wc + n * 16 + lrow) * 64 + ks * 32 + lk];
#pragma unroll
      for (int m = 0; m < 4; ++m)
#pragma unroll
        for (int n = 0; n < 4; ++n)
          acc[m][n] = __builtin_amdgcn_mfma_f32_16x16x32_bf16(af[m], bg[n], acc[m][n], 0, 0, 0);
    }
    __syncthreads();
  }
#pragma unroll
  for (int m = 0; m < 4; ++m)
#pragma unroll
    for (int n = 0; n < 4; ++n) {
      int r0 = wr + m * 16 + (lane >> 4) * 4;
      int c0 = bcol + wc + n * 16 + (lane & 15);
#pragma unroll
      for (int r = 0; r < 4; ++r)
        atomicAdd(&C[(size_t)(r0 + r) * 512 + c0], acc[m][n][r]);
    }
}

__global__ void k_init_out(float* __restrict__ out, const float* __restrict__ bout) {
  int i = blockIdx.x * 256 + threadIdx.x;   // 128*512
  out[i] = bout[i & 511];
}

extern "C" void kernel_launch(void* const* d_in, const int* in_sizes, int n_in,
                              void* d_out, int out_size, void* d_ws, size_t ws_size,
                              hipStream_t stream) {
  const float* x    = (const float*)d_in[0];
  const float* W1   = (const float*)d_in[1];
  const float* b1   = (const float*)d_in[2];
  const float* W2   = (const float*)d_in[3];
  const float* b2   = (const float*)d_in[4];
  const float* Wout = (const float*)d_in[5];
  const float* bout = (const float*)d_in[6];
  float* out = (float*)d_out;
  (void)in_sizes; (void)n_in; (void)out_size;

  char* ws = (char*)d_ws;
  size_t off = 0;
  auto alloc = [&](size_t bytes) -> void* {
    void* p = ws + off;
    off += (bytes + 255) & ~(size_t)255;
    return p;
  };
  unsigned short* W1cat = (unsigned short*)alloc((size_t)2048 * 2048 * 2);  // 8 MiB
  unsigned short* W2cat = (unsigned short*)alloc((size_t)2048 * 4096 * 2);  // 16 MiB
  unsigned short* Wocat = (unsigned short*)alloc((size_t)512 * 4096 * 2);   // 4 MiB
  unsigned short* ACC   = (unsigned short*)alloc((size_t)128 * 2048 * 2);   // 0.5 MiB
  const size_t fixed = off;

  // largest row-chunk (multiple of 1024) whose Xcat+S1 fit in ws
  int rows_c = 16384;
  while (rows_c > 1024) {
    size_t per = 2 * (((size_t)rows_c * 2048 * 2 + 255) & ~(size_t)255);
    if (fixed + per <= ws_size) break;
    rows_c >>= 1;
  }
  unsigned short* Xcat = (unsigned short*)alloc((size_t)rows_c * 2048 * 2);
  unsigned short* S1c  = (unsigned short*)alloc((size_t)rows_c * 2048 * 2);

  // weight splits (once per call)
  k_split<<<(2048 * 1024 + 255) / 256, 256, 0, stream>>>(W1, W1cat, 10, (size_t)2048 * 1024);
  k_split<<<(2048 * 2048 + 255) / 256, 256, 0, stream>>>(W2, W2cat, 11, (size_t)2048 * 2048);
  k_split<<<(512 * 2048 + 255) / 256, 256, 0, stream>>>(Wout, Wocat, 11, (size_t)512 * 2048);

  const int nch = 16384 / rows_c;
  for (int c = 0; c < nch; ++c) {
    k_split<<<rows_c * 4, 256, 0, stream>>>(x + (size_t)c * rows_c * 1024, Xcat, 10,
                                            (size_t)rows_c * 1024);
    k_gemm_lif<1><<<dim3(rows_c / 256, 8), 512, 0, stream>>>(Xcat, W1cat, b1, S1c, 0);
    k_gemm_lif<2><<<dim3(rows_c / 256, 8), 512, 0, stream>>>(S1c, W2cat, b2, ACC,
                                                             c * (rows_c / 128));
  }
  k_init_out<<<256, 256, 0, stream>>>(out, bout);
  k_gemm3<<<dim3(1, 4, 16), 256, 0, stream>>>(ACC, Wocat, out);
}

// Round 7
// 420.085 us; speedup vs baseline: 1.2995x; 1.0833x over previous
//
#include <hip/hip_runtime.h>

// SpikingNetwork: B=128 T=128 I=1024 H1=2048 H2=2048 O=512
// R7: register-pipelined fragment reads. Same geometry as R6 (256x256 block
//   tile, 8 waves of 128x64, BK=64, 2x64KB dbuf, row-XOR swizzle, bunched
//   stage at p0, fused LIF epilogue) but each phase issues the NEXT phase's
//   ds_reads (inline asm) and waits counted lgkmcnt(4|8) — previous reads
//   guaranteed (DS in-order), new ones fly under the MFMA burst. 2 barriers
//   per K-tile: {vmcnt(0)+bar} end-p2 (stage RAW for p3 early reads from
//   next slot), {bar} tile end (WAR; all slot-t reads lgkm-complete by then).
// Numerics: GEMM1 3-term split-bf16 (K'=3072), GEMM2 2-term (A=binary s1
//   exact in bf16, K'=4096), GEMM3 split-K atomic. All f32 accumulate.

typedef unsigned long long u64;
typedef __attribute__((ext_vector_type(4))) float f32x4;
typedef __attribute__((ext_vector_type(8))) short bf16x8;

__device__ __forceinline__ unsigned short f2bf(float f) {
  unsigned u = __float_as_uint(f);
  u += 0x7fff + ((u >> 16) & 1);   // RNE
  return (unsigned short)(u >> 16);
}
__device__ __forceinline__ float bf2f(unsigned short h) {
  return __uint_as_float(((unsigned)h) << 16);
}
__device__ __forceinline__ void gld_lds16(const unsigned short* g, unsigned short* l) {
  __builtin_amdgcn_global_load_lds((const __attribute__((address_space(1))) void*)g,
                                   (__attribute__((address_space(3))) void*)l, 16, 0, 0);
}

// src: R x K f32 (K = 1<<lgK) -> dst: R x 2K bf16 rows [hi | lo]
__global__ void k_split(const float* __restrict__ src, unsigned short* __restrict__ dst,
                        int lgK, size_t total) {
  size_t i = (size_t)blockIdx.x * 256 + threadIdx.x;
  if (i >= total) return;
  const int K = 1 << lgK;
  size_t r = i >> lgK;
  int k = (int)(i & (size_t)(K - 1));
  float f = src[i];
  unsigned short hi = f2bf(f);
  unsigned short lo = f2bf(f - bf2f(hi));
  size_t o = (r << (lgK + 1)) + (size_t)k;
  dst[o] = hi;
  dst[o + K] = lo;
}

// 4x ds_read_b128 from base + m*2048 (m-th 16-row fragment group)
#define DSR4(D, BASE)                                                          \
  do {                                                                         \
    asm volatile("ds_read_b128 %0, %1" : "=v"(D[0]) : "v"(BASE));              \
    asm volatile("ds_read_b128 %0, %1 offset:2048" : "=v"(D[1]) : "v"(BASE));  \
    asm volatile("ds_read_b128 %0, %1 offset:4096" : "=v"(D[2]) : "v"(BASE));  \
    asm volatile("ds_read_b128 %0, %1 offset:6144" : "=v"(D[3]) : "v"(BASE));  \
  } while (0)
#define WAITL(N)                                                               \
  do {                                                                         \
    asm volatile("s_waitcnt lgkmcnt(" #N ")" ::: "memory");                    \
    __builtin_amdgcn_sched_barrier(0);                                         \
  } while (0)
#define VM0() asm volatile("s_waitcnt vmcnt(0)" ::: "memory")
#define BAR() __builtin_amdgcn_s_barrier()
#define MFMA16(MH, AF, BG)                                                     \
  _Pragma("unroll")                                                            \
  for (int m = 0; m < 4; ++m)                                                  \
    _Pragma("unroll")                                                          \
    for (int n = 0; n < 4; ++n)                                                \
      acc[(MH)*4 + m][n] = __builtin_amdgcn_mfma_f32_16x16x32_bf16(            \
          AF[m], BG[n], acc[(MH)*4 + m][n], 0, 0, 0);

// Fused pipelined GEMM + LIF. Block tile 256x256 (2 batches' full time
// series x 256 cols). LAYER 1: NKT=48 (3-term); LAYER 2: NKT=64 (2-term).
template <int LAYER>
__global__ __launch_bounds__(512, 2)
void k_gemm_lif(const unsigned short* __restrict__ A,
                const unsigned short* __restrict__ Bw,
                const float* __restrict__ bias,
                unsigned short* __restrict__ out, int b0) {
  __shared__ __align__(128) char lds[132096];  // 2x64KB slots; epi 128x258 f32
  const int NKT = (LAYER == 1) ? 48 : 64;
  const int ldB = (LAYER == 1) ? 2048 : 4096;
  const int tid  = threadIdx.x;
  const int lane = tid & 63;
  const int w    = tid >> 6;                 // 0..7
  const int wm = w >> 2, wn = w & 3;         // 2M x 4N waves
  const int wr = wm * 128, wc = wn * 64;     // wave tile 128x64
  const int lrow = lane & 15, t4 = lane >> 4;
  const int brow = blockIdx.x * 256, bcol = blockIdx.y * 256;

  f32x4 acc[8][4];
#pragma unroll
  for (int m = 0; m < 8; ++m)
#pragma unroll
    for (int n = 0; n < 4; ++n) acc[m][n] = (f32x4){0.f, 0.f, 0.f, 0.f};

  // LDS addressing for swizzled fragment reads: row&7 == lrow&7 for every
  // fragment row, so the chunk index ch = (ks*4+t4)^(lrow&7) is per-lane
  // constant per ks; fragment m is base + m*2048 (offset: immediate).
  const unsigned ldsb = (unsigned)(size_t)(__attribute__((address_space(3))) char*)lds;
  const unsigned cA   = (unsigned)((wr + lrow) * 128);
  const unsigned cB   = (unsigned)(32768 + (wc + lrow) * 128);
  const unsigned ch0  = (unsigned)(((t4) ^ (lrow & 7)) * 16);
  const unsigned ch1  = (unsigned)(((4 + t4) ^ (lrow & 7)) * 16);

  // Stage ALL of K-tile tt (A 256x64 + B 256x64 = 4096 chunks, 8/thread)
  // into slot tt&1. LDS dest linear (gld_lds constraint); global source col
  // pre-swizzled (chunk ^ row&7) so the swizzled ds_read recovers linear K.
  auto stage_tile = [&](int tt) {
    if (tt >= NKT) return;
    const int kb = tt * 64;
    int aoff, boff;
    if (LAYER == 1) {
      aoff = (kb < 1024) ? kb : kb - 1024;    // [Xhi,Xhi,Xlo]
      boff = (kb < 2048) ? kb : kb - 2048;    // [W1hi,W1lo,W1hi]
    } else {
      aoff = kb & 2047;                        // binary S1 twice
      boff = kb;                               // [W2hi|W2lo]
    }
    char* slot = lds + (tt & 1) * 65536;
#pragma unroll
    for (int j = 0; j < 4; ++j) {              // A: 2048 chunks
      const int c = tid + j * 512;
      const int r = c >> 3;
      const int scol = ((c & 7) ^ (r & 7)) * 8;
      gld_lds16(A + (size_t)(brow + r) * 2048 + aoff + scol,
                (unsigned short*)(slot + c * 16));
    }
#pragma unroll
    for (int j = 0; j < 4; ++j) {              // B: 2048 chunks
      const int c = tid + j * 512;
      const int r = c >> 3;
      const int scol = ((c & 7) ^ (r & 7)) * 8;
      gld_lds16(Bw + (size_t)(bcol + r) * ldB + boff + scol,
                (unsigned short*)(slot + 32768 + c * 16));
    }
  };

  bf16x8 afA[4], afB[4], bgA[4], bgB[4];

  // prologue: tile 0 staged + landed; early-read p0 frags (afA=MH0/ks0, bgA=ks0)
  stage_tile(0);
  VM0();
  BAR();
  DSR4(afA, ldsb + cA + ch0);
  DSR4(bgA, ldsb + cB + ch0);

#pragma unroll 1
  for (int t = 0; t < NKT; ++t) {
    const unsigned sA  = ldsb + (unsigned)((t & 1) * 65536);
    const unsigned sAn = ldsb + (unsigned)(((t + 1) & 1) * 65536);
    // ---- phase 0: MFMA(MH0,ks0) [afA,bgA]; read afB=MH1/ks0; stage t+1 ----
    stage_tile(t + 1);
    DSR4(afB, sA + cA + 8192 + ch0);
    WAITL(4);
    __builtin_amdgcn_s_setprio(1); MFMA16(0, afA, bgA); __builtin_amdgcn_s_setprio(0);
    // ---- phase 1: MFMA(MH1,ks0) [afB,bgA]; read afA=MH0/ks1, bgB=ks1 ----
    DSR4(afA, sA + cA + ch1);
    DSR4(bgB, sA + cB + ch1);
    WAITL(8);
    __builtin_amdgcn_s_setprio(1); MFMA16(1, afB, bgA); __builtin_amdgcn_s_setprio(0);
    // ---- phase 2: MFMA(MH0,ks1) [afA,bgB]; read afB=MH1/ks1 ----
    DSR4(afB, sA + cA + 8192 + ch1);
    WAITL(4);
    __builtin_amdgcn_s_setprio(1); MFMA16(0, afA, bgB); __builtin_amdgcn_s_setprio(0);
    VM0();   // stage(t+1) landed (issued ~2 phases ago); then all-wave visible
    BAR();
    // ---- phase 3: MFMA(MH1,ks1) [afB,bgB]; early-read t+1's p0 frags ----
    if (t + 1 < NKT) {
      DSR4(afA, sAn + cA + ch0);
      DSR4(bgA, sAn + cB + ch0);
      WAITL(8);
    } else {
      WAITL(0);
    }
    __builtin_amdgcn_s_setprio(1); MFMA16(1, afB, bgB); __builtin_amdgcn_s_setprio(0);
    BAR();   // tile boundary: slot-t reads complete (lgkm-counted above) -> WAR safe
  }

  // ---- fused LIF epilogue: two 64-t halves, 128x258 f32 LDS tile ----
  float* Ct = (float*)lds;
  const int colT  = tid & 255;
  const int batch = tid >> 8;                // 2 batches x 256 cols = 512 scanners
  const float bs = bias[bcol + colT];
  float v = 0.f;
  int cnt = 0;
  unsigned short* sp = nullptr;
  if (LAYER == 1) sp = out + (size_t)(brow + batch * 128) * 2048 + bcol + colT;
#pragma unroll
  for (int h = 0; h < 2; ++h) {
    __syncthreads();
#pragma unroll
    for (int mm = 0; mm < 4; ++mm) {
      const int m = h * 4 + mm;              // frag m covers t = m*16..m*16+15
#pragma unroll
      for (int n = 0; n < 4; ++n) {
        const int lr  = wm * 64 + mm * 16 + t4 * 4;   // batch*64 + t-within-half
        const int col = wc + n * 16 + lrow;
#pragma unroll
        for (int r = 0; r < 4; ++r) Ct[(lr + r) * 258 + col] = acc[m][n][r];
      }
    }
    __syncthreads();
    if (LAYER == 1) {
#pragma unroll 4
      for (int tl = 0; tl < 64; ++tl) {
        const float xx = Ct[(batch * 64 + tl) * 258 + colT] + bs;
        v = 0.9f * xx + v - ((xx > 1.0f) ? 1.0f : 0.0f);
        sp[(size_t)(h * 64 + tl) * 2048] =
            (v > 1.0f) ? (unsigned short)0x3F80 : (unsigned short)0;
      }
    } else {
#pragma unroll 4
      for (int tl = 0; tl < 64; ++tl) {
        const float xx = Ct[(batch * 64 + tl) * 258 + colT] + bs;
        v = 0.9f * xx + v - ((xx > 1.0f) ? 1.0f : 0.0f);
        cnt += (v > 1.0f);
      }
    }
  }
  if (LAYER == 2)
    out[(size_t)(b0 + 2 * blockIdx.x + batch) * 2048 + bcol + colT] =
        f2bf((float)cnt * 0.0078125f);
}

// out(128x512) += ACC(128x2048 bf16) @ Wocat^T over K-slice z*256..+256, atomic
__global__ void k_gemm3(const unsigned short* __restrict__ A,
                        const unsigned short* __restrict__ B,
                        float* __restrict__ C) {
  __shared__ __align__(16) unsigned short Asm[128 * 64];
  __shared__ __align__(16) unsigned short Bsm[128 * 64];
  const int tid  = threadIdx.x;
  const int bcol = blockIdx.y * 128;
  const int k0   = blockIdx.z * 256;
  const int lane = tid & 63;
  const int w    = tid >> 6;
  const int wr = (w >> 1) * 64, wc = (w & 1) * 64;
  const int lrow = lane & 15, lk = (lane >> 4) * 8;

  f32x4 acc[4][4];
#pragma unroll
  for (int m = 0; m < 4; ++m)
#pragma unroll
    for (int n = 0; n < 4; ++n) acc[m][n] = (f32x4){0.f, 0.f, 0.f, 0.f};

  for (int kt = 0; kt < 4; ++kt) {
    const int kb = k0 + kt * 64;
#pragma unroll
    for (int i = 0; i < 4; ++i) {
      int c = tid + i * 256;
      int row = c >> 3, kc = (c & 7) * 8;
      gld_lds16(A + (size_t)row * 2048 + (kb & 2047) + kc, &Asm[c * 8]);
      gld_lds16(B + (size_t)(bcol + row) * 4096 + kb + kc, &Bsm[c * 8]);
    }
    __syncthreads();
#pragma unroll
    for (int ks = 0; ks < 2; ++ks) {
      bf16x8 af[4], bg[4];
#pragma unroll
      for (int m = 0; m < 4; ++m)
        af[m] = *(const bf16x8*)&Asm[(wr + m * 16 + lrow) * 64 + ks * 32 + lk];
#pragma unroll
      for (int n = 0; n < 4; ++n)
        bg[n] = *(const bf16x8*)&Bsm[(wc + n * 16 + lrow) * 64 + ks * 32 + lk];
#pragma unroll
      for (int m = 0; m < 4; ++m)
#pragma unroll
        for (int n = 0; n < 4; ++n)
          acc[m][n] = __builtin_amdgcn_mfma_f32_16x16x32_bf16(af[m], bg[n], acc[m][n], 0, 0, 0);
    }
    __syncthreads();
  }
#pragma unroll
  for (int m = 0; m < 4; ++m)
#pragma unroll
    for (int n = 0; n < 4; ++n) {
      int r0 = wr + m * 16 + (lane >> 4) * 4;
      int c0 = bcol + wc + n * 16 + (lane & 15);
#pragma unroll
      for (int r = 0; r < 4; ++r)
        atomicAdd(&C[(size_t)(r0 + r) * 512 + c0], acc[m][n][r]);
    }
}

__global__ void k_init_out(float* __restrict__ out, const float* __restrict__ bout) {
  int i = blockIdx.x * 256 + threadIdx.x;   // 128*512
  out[i] = bout[i & 511];
}

extern "C" void kernel_launch(void* const* d_in, const int* in_sizes, int n_in,
                              void* d_out, int out_size, void* d_ws, size_t ws_size,
                              hipStream_t stream) {
  const float* x    = (const float*)d_in[0];
  const float* W1   = (const float*)d_in[1];
  const float* b1   = (const float*)d_in[2];
  const float* W2   = (const float*)d_in[3];
  const float* b2   = (const float*)d_in[4];
  const float* Wout = (const float*)d_in[5];
  const float* bout = (const float*)d_in[6];
  float* out = (float*)d_out;
  (void)in_sizes; (void)n_in; (void)out_size;

  char* ws = (char*)d_ws;
  size_t off = 0;
  auto alloc = [&](size_t bytes) -> void* {
    void* p = ws + off;
    off += (bytes + 255) & ~(size_t)255;
    return p;
  };
  unsigned short* W1cat = (unsigned short*)alloc((size_t)2048 * 2048 * 2);  // 8 MiB
  unsigned short* W2cat = (unsigned short*)alloc((size_t)2048 * 4096 * 2);  // 16 MiB
  unsigned short* Wocat = (unsigned short*)alloc((size_t)512 * 4096 * 2);   // 4 MiB
  unsigned short* ACC   = (unsigned short*)alloc((size_t)128 * 2048 * 2);   // 0.5 MiB
  const size_t fixed = off;

  // largest row-chunk (multiple of 1024) whose Xcat+S1 fit in ws
  int rows_c = 16384;
  while (rows_c > 1024) {
    size_t per = 2 * (((size_t)rows_c * 2048 * 2 + 255) & ~(size_t)255);
    if (fixed + per <= ws_size) break;
    rows_c >>= 1;
  }
  unsigned short* Xcat = (unsigned short*)alloc((size_t)rows_c * 2048 * 2);
  unsigned short* S1c  = (unsigned short*)alloc((size_t)rows_c * 2048 * 2);

  // weight splits (once per call)
  k_split<<<(2048 * 1024 + 255) / 256, 256, 0, stream>>>(W1, W1cat, 10, (size_t)2048 * 1024);
  k_split<<<(2048 * 2048 + 255) / 256, 256, 0, stream>>>(W2, W2cat, 11, (size_t)2048 * 2048);
  k_split<<<(512 * 2048 + 255) / 256, 256, 0, stream>>>(Wout, Wocat, 11, (size_t)512 * 2048);

  const int nch = 16384 / rows_c;
  for (int c = 0; c < nch; ++c) {
    k_split<<<rows_c * 4, 256, 0, stream>>>(x + (size_t)c * rows_c * 1024, Xcat, 10,
                                            (size_t)rows_c * 1024);
    k_gemm_lif<1><<<dim3(rows_c / 256, 8), 512, 0, stream>>>(Xcat, W1cat, b1, S1c, 0);
    k_gemm_lif<2><<<dim3(rows_c / 256, 8), 512, 0, stream>>>(S1c, W2cat, b2, ACC,
                                                             c * (rows_c / 128));
  }
  k_init_out<<<256, 256, 0, stream>>>(out, bout);
  k_gemm3<<<dim3(1, 4, 16), 256, 0, stream>>>(ACC, Wocat, out);
}

// Round 8
// 323.418 us; speedup vs baseline: 1.6879x; 1.2989x over previous
//
#include <hip/hip_runtime.h>

// SpikingNetwork: B=128 T=128 I=1024 H1=2048 H2=2048 O=512
// R8: work-cut + VALU hoist on the R7 register-pipelined structure.
//   - GEMM2 drops the s1@W2lo term (K'=2048, NKT=32): s1 binary-exact, W2hi
//     rounding perturbs cur2 by ~5e-4 with NO cascade (last spiking layer);
//     est. absmax 0.0156 -> ~0.025 (threshold 0.0453). Revert if exceeded.
//   - staging addresses hoisted out of K-loop (per-thread voff/dst arrays);
//     per tile only wave-uniform aoff/boff pointer adds remain.
//   - k_split vectorized x4 (float4 load, 2x u64 store).
// Numerics: GEMM1 3-term split-bf16 (K'=3072), GEMM2 1-term hi (K'=2048),
//   GEMM3 2-term split-K atomic. All f32 accumulate.

typedef unsigned long long u64;
typedef __attribute__((ext_vector_type(4))) float f32x4;
typedef __attribute__((ext_vector_type(8))) short bf16x8;

__device__ __forceinline__ unsigned short f2bf(float f) {
  unsigned u = __float_as_uint(f);
  u += 0x7fff + ((u >> 16) & 1);   // RNE
  return (unsigned short)(u >> 16);
}
__device__ __forceinline__ float bf2f(unsigned short h) {
  return __uint_as_float(((unsigned)h) << 16);
}
__device__ __forceinline__ void gld_lds16(const unsigned short* g, unsigned short* l) {
  __builtin_amdgcn_global_load_lds((const __attribute__((address_space(1))) void*)g,
                                   (__attribute__((address_space(3))) void*)l, 16, 0, 0);
}

// src: R x K f32 (K = 1<<lgK) -> dst: R x 2K bf16 rows [hi | lo], 4 elem/thread
__global__ void k_split4(const float4* __restrict__ src, unsigned short* __restrict__ dst,
                         int lgK, size_t total4) {
  size_t i = (size_t)blockIdx.x * 256 + threadIdx.x;
  if (i >= total4) return;
  const int K = 1 << lgK;
  size_t e = i << 2;
  size_t r = e >> lgK;
  int k = (int)(e & (size_t)(K - 1));
  float4 f = src[i];
  unsigned short h0 = f2bf(f.x), h1 = f2bf(f.y), h2 = f2bf(f.z), h3 = f2bf(f.w);
  unsigned short l0 = f2bf(f.x - bf2f(h0)), l1 = f2bf(f.y - bf2f(h1));
  unsigned short l2 = f2bf(f.z - bf2f(h2)), l3 = f2bf(f.w - bf2f(h3));
  size_t o = (r << (lgK + 1)) + (size_t)k;
  *(u64*)(dst + o)     = (u64)h0 | ((u64)h1 << 16) | ((u64)h2 << 32) | ((u64)h3 << 48);
  *(u64*)(dst + o + K) = (u64)l0 | ((u64)l1 << 16) | ((u64)l2 << 32) | ((u64)l3 << 48);
}

// 4x ds_read_b128 from base + m*2048 (m-th 16-row fragment group)
#define DSR4(D, BASE)                                                          \
  do {                                                                         \
    asm volatile("ds_read_b128 %0, %1" : "=v"(D[0]) : "v"(BASE));              \
    asm volatile("ds_read_b128 %0, %1 offset:2048" : "=v"(D[1]) : "v"(BASE));  \
    asm volatile("ds_read_b128 %0, %1 offset:4096" : "=v"(D[2]) : "v"(BASE));  \
    asm volatile("ds_read_b128 %0, %1 offset:6144" : "=v"(D[3]) : "v"(BASE));  \
  } while (0)
#define WAITL(N)                                                               \
  do {                                                                         \
    asm volatile("s_waitcnt lgkmcnt(" #N ")" ::: "memory");                    \
    __builtin_amdgcn_sched_barrier(0);                                         \
  } while (0)
#define VM0() asm volatile("s_waitcnt vmcnt(0)" ::: "memory")
#define BAR() __builtin_amdgcn_s_barrier()
#define MFMA16(MH, AF, BG)                                                     \
  _Pragma("unroll")                                                            \
  for (int m = 0; m < 4; ++m)                                                  \
    _Pragma("unroll")                                                          \
    for (int n = 0; n < 4; ++n)                                                \
      acc[(MH)*4 + m][n] = __builtin_amdgcn_mfma_f32_16x16x32_bf16(            \
          AF[m], BG[n], acc[(MH)*4 + m][n], 0, 0, 0);

// Fused pipelined GEMM + LIF. Block tile 256x256 (2 batches' full time
// series x 256 cols). LAYER 1: NKT=48 (3-term); LAYER 2: NKT=32 (hi-only).
template <int LAYER>
__global__ __launch_bounds__(512, 2)
void k_gemm_lif(const unsigned short* __restrict__ A,
                const unsigned short* __restrict__ Bw,
                const float* __restrict__ bias,
                unsigned short* __restrict__ out, int b0) {
  __shared__ __align__(128) char lds[132096];  // 2x64KB slots; epi 128x258 f32
  const int NKT = (LAYER == 1) ? 48 : 32;
  const int ldB = (LAYER == 1) ? 2048 : 4096;
  const int tid  = threadIdx.x;
  const int lane = tid & 63;
  const int w    = tid >> 6;                 // 0..7
  const int wm = w >> 2, wn = w & 3;         // 2M x 4N waves
  const int wr = wm * 128, wc = wn * 64;     // wave tile 128x64
  const int lrow = lane & 15, t4 = lane >> 4;
  const int brow = blockIdx.x * 256, bcol = blockIdx.y * 256;

  f32x4 acc[8][4];
#pragma unroll
  for (int m = 0; m < 8; ++m)
#pragma unroll
    for (int n = 0; n < 4; ++n) acc[m][n] = (f32x4){0.f, 0.f, 0.f, 0.f};

  // Hoisted per-thread staging geometry (K-loop invariant). Global source
  // col pre-swizzled (chunk ^ row&7) so swizzled ds_read recovers linear K.
  int voffA[4], voffB[4];
  unsigned dstA[4], dstB[4];
#pragma unroll
  for (int j = 0; j < 4; ++j) {
    const int c = tid + j * 512;             // 2048 chunks each for A and B
    const int r = c >> 3;
    const int scol = ((c & 7) ^ (r & 7)) * 8;
    voffA[j] = (brow + r) * 2048 + scol;
    voffB[j] = (bcol + r) * ldB + scol;
    dstA[j] = (unsigned)c * 16;
    dstB[j] = 32768u + (unsigned)c * 16;
  }

  // Stage ALL of K-tile tt (A 256x64 + B 256x64, 8 chunks/thread) -> slot tt&1.
  auto stage_tile = [&](int tt) {
    if (tt >= NKT) return;
    const int kb = tt * 64;
    int aoff, boff;
    if (LAYER == 1) {
      aoff = (kb < 1024) ? kb : kb - 1024;    // [Xhi,Xhi,Xlo]
      boff = (kb < 2048) ? kb : kb - 2048;    // [W1hi,W1lo,W1hi]
    } else {
      aoff = kb;                               // binary S1 (K'=2048)
      boff = kb;                               // W2hi only
    }
    const unsigned short* Ap = A + aoff;       // wave-uniform pointer adds
    const unsigned short* Bp = Bw + boff;
    char* slot = lds + (tt & 1) * 65536;
#pragma unroll
    for (int j = 0; j < 4; ++j)
      gld_lds16(Ap + voffA[j], (unsigned short*)(slot + dstA[j]));
#pragma unroll
    for (int j = 0; j < 4; ++j)
      gld_lds16(Bp + voffB[j], (unsigned short*)(slot + dstB[j]));
  };

  // LDS fragment-read bases: row&7 == lrow&7 for every fragment row, so the
  // chunk index ch = (ks*4+t4)^(lrow&7) is per-lane constant per ks.
  const unsigned ldsb = (unsigned)(size_t)(__attribute__((address_space(3))) char*)lds;
  const unsigned cA   = (unsigned)((wr + lrow) * 128);
  const unsigned cB   = (unsigned)(32768 + (wc + lrow) * 128);
  const unsigned ch0  = (unsigned)(((t4) ^ (lrow & 7)) * 16);
  const unsigned ch1  = (unsigned)(((4 + t4) ^ (lrow & 7)) * 16);

  bf16x8 afA[4], afB[4], bgA[4], bgB[4];

  // prologue: tile 0 staged + landed; early-read p0 frags
  stage_tile(0);
  VM0();
  BAR();
  DSR4(afA, ldsb + cA + ch0);
  DSR4(bgA, ldsb + cB + ch0);

#pragma unroll 1
  for (int t = 0; t < NKT; ++t) {
    const unsigned sA  = ldsb + (unsigned)((t & 1) * 65536);
    const unsigned sAn = ldsb + (unsigned)(((t + 1) & 1) * 65536);
    // ---- phase 0: MFMA(MH0,ks0); read afB=MH1/ks0; stage t+1 ----
    stage_tile(t + 1);
    DSR4(afB, sA + cA + 8192 + ch0);
    WAITL(4);
    __builtin_amdgcn_s_setprio(1); MFMA16(0, afA, bgA); __builtin_amdgcn_s_setprio(0);
    // ---- phase 1: MFMA(MH1,ks0); read afA=MH0/ks1, bgB=ks1 ----
    DSR4(afA, sA + cA + ch1);
    DSR4(bgB, sA + cB + ch1);
    WAITL(8);
    __builtin_amdgcn_s_setprio(1); MFMA16(1, afB, bgA); __builtin_amdgcn_s_setprio(0);
    // ---- phase 2: MFMA(MH0,ks1); read afB=MH1/ks1 ----
    DSR4(afB, sA + cA + 8192 + ch1);
    WAITL(4);
    __builtin_amdgcn_s_setprio(1); MFMA16(0, afA, bgB); __builtin_amdgcn_s_setprio(0);
    VM0();   // stage(t+1) landed (issued ~2 phases ago); all-wave visible
    BAR();
    // ---- phase 3: MFMA(MH1,ks1); early-read t+1's p0 frags ----
    if (t + 1 < NKT) {
      DSR4(afA, sAn + cA + ch0);
      DSR4(bgA, sAn + cB + ch0);
      WAITL(8);
    } else {
      WAITL(0);
    }
    __builtin_amdgcn_s_setprio(1); MFMA16(1, afB, bgB); __builtin_amdgcn_s_setprio(0);
    BAR();   // tile boundary: slot-t reads lgkm-complete -> WAR safe
  }

  // ---- fused LIF epilogue: two 64-t halves, 128x258 f32 LDS tile ----
  float* Ct = (float*)lds;
  const int colT  = tid & 255;
  const int batch = tid >> 8;                // 2 batches x 256 cols = 512 scanners
  const float bs = bias[bcol + colT];
  float v = 0.f;
  int cnt = 0;
  unsigned short* sp = nullptr;
  if (LAYER == 1) sp = out + (size_t)(brow + batch * 128) * 2048 + bcol + colT;
#pragma unroll
  for (int h = 0; h < 2; ++h) {
    __syncthreads();
#pragma unroll
    for (int mm = 0; mm < 4; ++mm) {
      const int m = h * 4 + mm;              // frag m covers t = m*16..m*16+15
#pragma unroll
      for (int n = 0; n < 4; ++n) {
        const int lr  = wm * 64 + mm * 16 + t4 * 4;   // batch*64 + t-within-half
        const int col = wc + n * 16 + lrow;
#pragma unroll
        for (int r = 0; r < 4; ++r) Ct[(lr + r) * 258 + col] = acc[m][n][r];
      }
    }
    __syncthreads();
    if (LAYER == 1) {
#pragma unroll 4
      for (int tl = 0; tl < 64; ++tl) {
        const float xx = Ct[(batch * 64 + tl) * 258 + colT] + bs;
        v = 0.9f * xx + v - ((xx > 1.0f) ? 1.0f : 0.0f);
        sp[(size_t)(h * 64 + tl) * 2048] =
            (v > 1.0f) ? (unsigned short)0x3F80 : (unsigned short)0;
      }
    } else {
#pragma unroll 4
      for (int tl = 0; tl < 64; ++tl) {
        const float xx = Ct[(batch * 64 + tl) * 258 + colT] + bs;
        v = 0.9f * xx + v - ((xx > 1.0f) ? 1.0f : 0.0f);
        cnt += (v > 1.0f);
      }
    }
  }
  if (LAYER == 2)
    out[(size_t)(b0 + 2 * blockIdx.x + batch) * 2048 + bcol + colT] =
        f2bf((float)cnt * 0.0078125f);
}

// out(128x512) += ACC(128x2048 bf16) @ Wocat^T over K-slice z*256..+256, atomic
__global__ void k_gemm3(const unsigned short* __restrict__ A,
                        const unsigned short* __restrict__ B,
                        float* __restrict__ C) {
  __shared__ __align__(16) unsigned short Asm[128 * 64];
  __shared__ __align__(16) unsigned short Bsm[128 * 64];
  const int tid  = threadIdx.x;
  const int bcol = blockIdx.y * 128;
  const int k0   = blockIdx.z * 256;
  const int lane = tid & 63;
  const int w    = tid >> 6;
  const int wr = (w >> 1) * 64, wc = (w & 1) * 64;
  const int lrow = lane & 15, lk = (lane >> 4) * 8;

  f32x4 acc[4][4];
#pragma unroll
  for (int m = 0; m < 4; ++m)
#pragma unroll
    for (int n = 0; n < 4; ++n) acc[m][n] = (f32x4){0.f, 0.f, 0.f, 0.f};

  for (int kt = 0; kt < 4; ++kt) {
    const int kb = k0 + kt * 64;
#pragma unroll
    for (int i = 0; i < 4; ++i) {
      int c = tid + i * 256;
      int row = c >> 3, kc = (c & 7) * 8;
      gld_lds16(A + (size_t)row * 2048 + (kb & 2047) + kc, &Asm[c * 8]);
      gld_lds16(B + (size_t)(bcol + row) * 4096 + kb + kc, &Bsm[c * 8]);
    }
    __syncthreads();
#pragma unroll
    for (int ks = 0; ks < 2; ++ks) {
      bf16x8 af[4], bg[4];
#pragma unroll
      for (int m = 0; m < 4; ++m)
        af[m] = *(const bf16x8*)&Asm[(wr + m * 16 + lrow) * 64 + ks * 32 + lk];
#pragma unroll
      for (int n = 0; n < 4; ++n)
        bg[n] = *(const bf16x8*)&Bsm[(wc + n * 16 + lrow) * 64 + ks * 32 + lk];
#pragma unroll
      for (int m = 0; m < 4; ++m)
#pragma unroll
        for (int n = 0; n < 4; ++n)
          acc[m][n] = __builtin_amdgcn_mfma_f32_16x16x32_bf16(af[m], bg[n], acc[m][n], 0, 0, 0);
    }
    __syncthreads();
  }
#pragma unroll
  for (int m = 0; m < 4; ++m)
#pragma unroll
    for (int n = 0; n < 4; ++n) {
      int r0 = wr + m * 16 + (lane >> 4) * 4;
      int c0 = bcol + wc + n * 16 + (lane & 15);
#pragma unroll
      for (int r = 0; r < 4; ++r)
        atomicAdd(&C[(size_t)(r0 + r) * 512 + c0], acc[m][n][r]);
    }
}

__global__ void k_init_out(float* __restrict__ out, const float* __restrict__ bout) {
  int i = blockIdx.x * 256 + threadIdx.x;   // 128*512
  out[i] = bout[i & 511];
}

extern "C" void kernel_launch(void* const* d_in, const int* in_sizes, int n_in,
                              void* d_out, int out_size, void* d_ws, size_t ws_size,
                              hipStream_t stream) {
  const float* x    = (const float*)d_in[0];
  const float* W1   = (const float*)d_in[1];
  const float* b1   = (const float*)d_in[2];
  const float* W2   = (const float*)d_in[3];
  const float* b2   = (const float*)d_in[4];
  const float* Wout = (const float*)d_in[5];
  const float* bout = (const float*)d_in[6];
  float* out = (float*)d_out;
  (void)in_sizes; (void)n_in; (void)out_size;

  char* ws = (char*)d_ws;
  size_t off = 0;
  auto alloc = [&](size_t bytes) -> void* {
    void* p = ws + off;
    off += (bytes + 255) & ~(size_t)255;
    return p;
  };
  unsigned short* W1cat = (unsigned short*)alloc((size_t)2048 * 2048 * 2);  // 8 MiB
  unsigned short* W2cat = (unsigned short*)alloc((size_t)2048 * 4096 * 2);  // 16 MiB
  unsigned short* Wocat = (unsigned short*)alloc((size_t)512 * 4096 * 2);   // 4 MiB
  unsigned short* ACC   = (unsigned short*)alloc((size_t)128 * 2048 * 2);   // 0.5 MiB
  const size_t fixed = off;

  // largest row-chunk (multiple of 1024) whose Xcat+S1 fit in ws
  int rows_c = 16384;
  while (rows_c > 1024) {
    size_t per = 2 * (((size_t)rows_c * 2048 * 2 + 255) & ~(size_t)255);
    if (fixed + per <= ws_size) break;
    rows_c >>= 1;
  }
  unsigned short* Xcat = (unsigned short*)alloc((size_t)rows_c * 2048 * 2);
  unsigned short* S1c  = (unsigned short*)alloc((size_t)rows_c * 2048 * 2);

  // weight splits (once per call), 4 elem/thread
  k_split4<<<(2048 * 256 + 255) / 256, 256, 0, stream>>>((const float4*)W1, W1cat, 10,
                                                         (size_t)2048 * 256);
  k_split4<<<(2048 * 512 + 255) / 256, 256, 0, stream>>>((const float4*)W2, W2cat, 11,
                                                         (size_t)2048 * 512);
  k_split4<<<(512 * 512 + 255) / 256, 256, 0, stream>>>((const float4*)Wout, Wocat, 11,
                                                        (size_t)512 * 512);

  const int nch = 16384 / rows_c;
  for (int c = 0; c < nch; ++c) {
    k_split4<<<rows_c, 256, 0, stream>>>((const float4*)(x + (size_t)c * rows_c * 1024),
                                         Xcat, 10, (size_t)rows_c * 256);
    k_gemm_lif<1><<<dim3(rows_c / 256, 8), 512, 0, stream>>>(Xcat, W1cat, b1, S1c, 0);
    k_gemm_lif<2><<<dim3(rows_c / 256, 8), 512, 0, stream>>>(S1c, W2cat, b2, ACC,
                                                             c * (rows_c / 128));
  }
  k_init_out<<<256, 256, 0, stream>>>(out, bout);
  k_gemm3<<<dim3(1, 4, 16), 256, 0, stream>>>(ACC, Wocat, out);
}